// Round 18
// baseline (120.046 us; speedup 1.0000x reference)
//
#include <hip/hip_runtime.h>
#include <hip/hip_bf16.h>

// Single-head causal self-attention, B=4 T=4096 C=1024 H=128, f32 in/out.
// R17 best config + attn launch_bounds(512,6): VGPR demand is only 60 now
// (swapped QK^T), so the 85-VGPR cap is safe and 3 blocks/CU (24 waves/CU)
// become resident (LDS 51200*3 = 150KB <= 160KB).
// prep_w: W -> Wf bf16 in MFMA-FRAGMENT ORDER (Q prescaled by H^-0.5).
// proj:   512 blocks x 32 rows, 512 threads (8 waves, 3 n-frags each);
//         x staged ONCE in LDS (32x1024 bf16 = 64KB, XOR-swizzled); k-loop
//         BARRIER-FREE: W frags straight from L2 (coalesced), x from LDS.
// attn:   flash causal, 512-thr: QBLK=128 = 8 waves x 16 q-rows, K/V staged
//         via global_load_lds into XOR-swizzled LDS. SWAPPED QK^T: lane holds
//         one q-row's 16 S-values -> in-lane softmax tree + 2 shfl.
//         P spill packed as ds_write_b64. kv-split chunk=256, heavy-first,
//         XCD-pinned batch. Partials bf16.
// combine: grid (128,4): 32 rows/block, <=16 partials, 16 acc/thread.
//
// ws map (bytes):
//   Wf    [0,        786432)
//   Qb    [786432,   +4MB)
//   Kb    [+4MB)
//   Vt    [+4MB)                      -> 13369344
//   Opart [13369344, +1088*32KB)      -> 49020928   (bf16)
//   ml    [49020928, +1114112)        -> 50135040

typedef unsigned short u16;
typedef __attribute__((ext_vector_type(8))) __bf16 bf16x8;
typedef __attribute__((ext_vector_type(8))) u16 u16x8;
typedef __attribute__((ext_vector_type(4))) u16 u16x4;
typedef __attribute__((ext_vector_type(4))) float f32x4;

#define T_DIM 4096
#define C_DIM 1024
#define H_DIM 128
#define EPB 272  // entries per batch: sum_{qb<32} ceil((qb+1)/2), chunk=256
#define WS_SPLIT_NEED 50135040ull

static __device__ __forceinline__ f32x4 mfma16x16(u16x8 a, u16x8 b, f32x4 c) {
  return __builtin_amdgcn_mfma_f32_16x16x32_bf16(
      __builtin_bit_cast(bf16x8, a), __builtin_bit_cast(bf16x8, b), c, 0, 0, 0);
}

static __device__ __forceinline__ u16 f2bf(float f) {
  __hip_bfloat16 h = __float2bfloat16(f);
  return __builtin_bit_cast(u16, h);
}

static __device__ __forceinline__ float bf2f(u16 u) {
  unsigned x = (unsigned)u << 16;
  return __builtin_bit_cast(float, x);
}

// async global->LDS, 16B per lane; lptr must be wave-uniform base.
static __device__ __forceinline__ void gll16(const u16* g, u16* l) {
  __builtin_amdgcn_global_load_lds(
      (const __attribute__((address_space(1))) void*)(void*)g,
      (__attribute__((address_space(3))) void*)l, 16, 0, 0);
}

// ---------------------------------------------------------------- prep_w ----
// grid 192 x 256: each thread emits one u16x8 of Wf (coalesced writes).
__global__ __launch_bounds__(256) void prep_w_kernel(
    const float* __restrict__ wk, const float* __restrict__ wq,
    const float* __restrict__ wv, u16* __restrict__ Wf) {
  const int oid = blockIdx.x * 256 + threadIdx.x;  // [0, 49152)
  const int w = oid >> 14;
  const int r = oid & 16383;
  const int nb = r >> 11;
  const int kb = (r >> 6) & 31;
  const int lane = r & 63;
  const int g = lane >> 4, lq = lane & 15;
  const float* W = (w == 0) ? wk : (w == 1) ? wq : wv;
  const float sc = (w == 1) ? 0.08838834764831845f : 1.0f;
  const int k0 = kb * 32 + g * 8;
  const int n = nb * 16 + lq;
  u16x8 o;
#pragma unroll
  for (int j = 0; j < 8; ++j) o[j] = f2bf(W[(size_t)(k0 + j) * H_DIM + n] * sc);
  *(u16x8*)&Wf[(size_t)oid * 8] = o;
}

// ------------------------------------------------------------------ proj ----
// 512 blocks x 32 rows, 512 threads: 8 waves, wave owns cols384
// wave*48 + j*16 + lq (j=0..2). Barrier-free k-loop, W frags from L2.
__global__ __launch_bounds__(512, 2) void proj_kernel(
    const float* __restrict__ x, const u16* __restrict__ Wf,
    u16* __restrict__ Qb, u16* __restrict__ Kb, u16* __restrict__ Vt) {
  __shared__ __attribute__((aligned(16))) u16 smem[32 * 1024];  // 64 KB
  const int m0 = blockIdx.x * 32;
  const int t = threadIdx.x;
  const int wave = t >> 6, lane = t & 63;
  const int g = lane >> 4, lq = lane & 15;
  const int lsw = lq & 7;

  // stage x: 32 rows x 1024 cols f32 -> bf16, swizzled 16B chunks
#pragma unroll
  for (int p = 0; p < 8; ++p) {
    int c = p * 512 + t;          // chunk id [0, 4096)
    int row = c >> 7, cc = c & 127;
    const float* xp = &x[(size_t)(m0 + row) * C_DIM + cc * 8];
    float4 v0 = *(const float4*)xp;
    float4 v1 = *(const float4*)(xp + 4);
    u16x8 bv;
    bv[0] = f2bf(v0.x); bv[1] = f2bf(v0.y); bv[2] = f2bf(v0.z); bv[3] = f2bf(v0.w);
    bv[4] = f2bf(v1.x); bv[5] = f2bf(v1.y); bv[6] = f2bf(v1.z); bv[7] = f2bf(v1.w);
    *(u16x8*)&smem[row * 1024 + ((cc ^ (row & 7)) * 8)] = bv;
  }
  __syncthreads();

  f32x4 acc[2][3] = {};

  for (int k0 = 0; k0 < C_DIM; k0 += 64) {  // NO barriers inside
    const int kb0 = k0 >> 5;
#pragma unroll
    for (int kk = 0; kk < 2; ++kk) {
      u16x8 af[2], bfr[3];
#pragma unroll
      for (int i = 0; i < 2; ++i)
        af[i] = *(const u16x8*)&smem[(i * 16 + lq) * 1024 +
                                     ((((k0 >> 3) + kk * 4 + g) ^ lsw) * 8)];
#pragma unroll
      for (int j = 0; j < 3; ++j) {
        int nb = wave * 3 + j;  // frag covers cols nb*16..+15
        bfr[j] = *(const u16x8*)&Wf[(size_t)(nb * 32 + kb0 + kk) * 512 +
                                    lane * 8];
      }
#pragma unroll
      for (int i = 0; i < 2; ++i)
#pragma unroll
        for (int j = 0; j < 3; ++j)
          acc[i][j] = mfma16x16(af[i], bfr[j], acc[i][j]);
    }
  }

#pragma unroll
  for (int j = 0; j < 3; ++j) {  // K and Q direct writes (wave-uniform branch)
    const int c384 = wave * 48 + j * 16;
    const int which = c384 >> 7;
    const int col = (c384 & 127) + lq;
    if (which == 0) {
#pragma unroll
      for (int i = 0; i < 2; ++i)
#pragma unroll
        for (int r = 0; r < 4; ++r)
          Kb[(size_t)(m0 + i * 16 + g * 4 + r) * H_DIM + col] =
              f2bf(acc[i][j][r]);
    } else if (which == 1) {
#pragma unroll
      for (int i = 0; i < 2; ++i)
#pragma unroll
        for (int r = 0; r < 4; ++r)
          Qb[(size_t)(m0 + i * 16 + g * 4 + r) * H_DIM + col] =
              f2bf(acc[i][j][r]);  // Wq prescaled in prep_w
    }
  }
  __syncthreads();  // all x-LDS reads done; reuse smem for V transpose
#pragma unroll
  for (int j = 0; j < 3; ++j) {  // V -> LDS transposed [128 h][32 m] pad 40
    const int c384 = wave * 48 + j * 16;
    if ((c384 >> 7) == 2) {
      const int v = (c384 & 127) + lq;
#pragma unroll
      for (int i = 0; i < 2; ++i)
#pragma unroll
        for (int r = 0; r < 4; ++r)
          smem[v * 40 + i * 16 + g * 4 + r] = f2bf(acc[i][j][r]);
    }
  }
  __syncthreads();
  {
    const int b = m0 >> 12;
    const int t0 = m0 & 4095;
    int h = t >> 2, mc = (t & 3) * 8;  // 512 thr x 8 = 128x32
    *(u16x8*)&Vt[(size_t)b * (H_DIM * T_DIM) + (size_t)h * T_DIM + t0 + mc] =
        *(const u16x8*)&smem[h * 40 + mc];
  }
}

// ------------------------------------------------------------------ attn ----
// 512 threads: 8 waves x 16 q-rows = QBLK 128 sharing one K/V staging via
// global_load_lds (pre-swizzled source). SWAPPED QK^T: s = mfma(K,Q) puts a
// full q-row (16 S values) in each lane -> in-lane softmax tree + 2 shfl.
// P spill: 4x ds_write_b64 per wave (packed).
// launch_bounds(512,6): 3 blocks/CU (VGPR demand 60 <= ~85 cap; R7's spill
// trap no longer applies after the swapped-QK^T register diet).
// split: 1088 blocks, XCD-pinned batch, heavy entries first, chunk=256.
__global__ __launch_bounds__(512, 6) void attn_kernel(
    const u16* __restrict__ Qb, const u16* __restrict__ Kb,
    const u16* __restrict__ Vt, float* __restrict__ out,
    u16* __restrict__ Opart, float* __restrict__ ml, int split) {
  __shared__ __attribute__((aligned(16))) u16 Kl[64 * 128];  // swizzled
  __shared__ __attribute__((aligned(16))) u16 Vl[128 * 64];  // swizzled
  __shared__ __attribute__((aligned(16))) u16 Pl[8][16 * 72];
  const int t = threadIdx.x;
  const int wave = t >> 6, lane = t & 63;
  const int g = lane >> 4, lq = lane & 15;
  const int lsw = lane & 7;  // read-side swizzle key (= row&7 for row=16nf+lq)

  int b, qb, kvb, kve, pid;
  if (split) {
    int bid = (int)blockIdx.x;  // 1088 linear
    int xcd = bid & 7;
    b = xcd >> 1;  // batch pinned to an XCD pair -> K/V L2-local
    int e = (EPB - 1) - ((bid >> 3) * 2 + (bid & 1));  // heavy-first
    int a = 0;
#pragma unroll
    for (int c = 1; c <= 15; ++c)
      if (e >= c * (c + 1)) a = c;
    int off = e - a * (a + 1);
    int d = off / (a + 1);
    int ch = off - d * (a + 1);
    qb = 2 * a + d;
    kvb = ch * 256;
    pid = b * EPB + e;
    int kv_full = qb * 128 + 128;
    kve = (kvb + 256 < kv_full) ? kvb + 256 : kv_full;
  } else {
    b = (int)blockIdx.x & 3;
    qb = 31 - ((int)blockIdx.x >> 2);
    kvb = 0;
    kve = qb * 128 + 128;
    pid = 0;
  }
  const int rowq = qb * 128 + wave * 16;  // wave's first q-row
  const int qrow = rowq + lq;             // this lane's q row (swapped layout)

  u16x8 qf[4];  // 16 q-rows x 128, A-frag layout (prescaled)
  {
    const u16* Qp = Qb + (size_t)(b * T_DIM + qrow) * H_DIM;
#pragma unroll
    for (int c = 0; c < 4; ++c) qf[c] = *(const u16x8*)&Qp[c * 32 + g * 8];
  }

  f32x4 ao[8] = {};
  float m_run = -INFINITY, l_run = 0.f;  // per-lane scalars (q = qrow)

  const u16* Kg0 = Kb + (size_t)b * T_DIM * H_DIM;
  const u16* Vg0 = Vt + (size_t)b * H_DIM * T_DIM;

  for (int kv0 = kvb; kv0 < kve; kv0 += 64) {
    __syncthreads();
    // K tile [64][128]: 2 issues/wave, each 4 rows (1KB).
#pragma unroll
    for (int i = 0; i < 2; ++i) {
      int r0 = (i * 8 + wave) * 4;
      int r = r0 + (lane >> 4);
      int csrc = (lane & 15) ^ (r & 7);
      gll16(&Kg0[(size_t)(kv0 + r) * H_DIM + csrc * 8], &Kl[r0 * 128]);
    }
    // V tile [128][64]: 2 issues/wave, each 8 rows (1KB).
#pragma unroll
    for (int i = 0; i < 2; ++i) {
      int h0 = (i * 8 + wave) * 8;
      int h = h0 + (lane >> 3);
      int csrc = (lane & 7) ^ (lane >> 3);
      gll16(&Vg0[(size_t)h * T_DIM + kv0 + csrc * 8], &Vl[h0 * 64]);
    }
    __syncthreads();

    if (kv0 > rowq + 15) continue;  // fully masked for this wave (uniform)

    // S^T = mfma(K, Q): lane (g,lq) holds S[qrow][kv0 + nf*16 + 4g + r]
    f32x4 s[4];
#pragma unroll
    for (int nf = 0; nf < 4; ++nf) s[nf] = f32x4{0.f, 0.f, 0.f, 0.f};
#pragma unroll
    for (int nf = 0; nf < 4; ++nf)
#pragma unroll
      for (int c = 0; c < 4; ++c) {
        u16x8 kf = *(const u16x8*)&Kl[(nf * 16 + lq) * 128 +
                                      (((c * 4 + g) ^ lsw) * 8)];
        s[nf] = mfma16x16(kf, qf[c], s[nf]);
      }

    if (kv0 + 63 > rowq) {  // diagonal overlap: elementwise causal mask
      const int kb = kv0 + g * 4;
#pragma unroll
      for (int nf = 0; nf < 4; ++nf)
#pragma unroll
        for (int r = 0; r < 4; ++r)
          if (kb + nf * 16 + r > qrow) s[nf][r] = -INFINITY;
    }

    // softmax: in-lane tree over 16 values + cross-g (xor 16, 32)
    float t0 = fmaxf(fmaxf(s[0][0], s[0][1]), fmaxf(s[0][2], s[0][3]));
    float t1 = fmaxf(fmaxf(s[1][0], s[1][1]), fmaxf(s[1][2], s[1][3]));
    float t2 = fmaxf(fmaxf(s[2][0], s[2][1]), fmaxf(s[2][2], s[2][3]));
    float t3 = fmaxf(fmaxf(s[3][0], s[3][1]), fmaxf(s[3][2], s[3][3]));
    float pmax = fmaxf(fmaxf(t0, t1), fmaxf(t2, t3));
    pmax = fmaxf(pmax, __shfl_xor(pmax, 16));
    pmax = fmaxf(pmax, __shfl_xor(pmax, 32));

    float mn = fmaxf(m_run, pmax);
    float al = __expf(m_run - mn);
    m_run = mn;
#pragma unroll
    for (int nf = 0; nf < 4; ++nf)
#pragma unroll
      for (int r = 0; r < 4; ++r) s[nf][r] = __expf(s[nf][r] - mn);
    float u0 = (s[0][0] + s[0][1]) + (s[0][2] + s[0][3]);
    float u1 = (s[1][0] + s[1][1]) + (s[1][2] + s[1][3]);
    float u2 = (s[2][0] + s[2][1]) + (s[2][2] + s[2][3]);
    float u3 = (s[3][0] + s[3][1]) + (s[3][2] + s[3][3]);
    float ps = (u0 + u1) + (u2 + u3);
    ps += __shfl_xor(ps, 16);
    ps += __shfl_xor(ps, 32);
    l_run = l_run * al + ps;

    // defer-rescale: only broadcast+rescale when some row's max moved
    if (!__all(al == 1.f)) {
      float alr[4];
#pragma unroll
      for (int r = 0; r < 4; ++r) alr[r] = __shfl(al, g * 4 + r);
#pragma unroll
      for (int h8 = 0; h8 < 8; ++h8)
#pragma unroll
        for (int r = 0; r < 4; ++r) ao[h8][r] *= alr[r];
    }

    // P (swapped layout) -> per-wave LDS, PACKED b64 writes (4 instrs)
#pragma unroll
    for (int nf = 0; nf < 4; ++nf) {
      u16x4 pw;
#pragma unroll
      for (int r = 0; r < 4; ++r) pw[r] = f2bf(s[nf][r]);
      *(u16x4*)&Pl[wave][lq * 72 + nf * 16 + g * 4] = pw;
    }

    u16x8 pf[2];
#pragma unroll
    for (int kk = 0; kk < 2; ++kk)
      pf[kk] = *(const u16x8*)&Pl[wave][lq * 72 + kk * 32 + g * 8];
#pragma unroll
    for (int h8 = 0; h8 < 8; ++h8)
#pragma unroll
      for (int kk = 0; kk < 2; ++kk) {
        u16x8 vf = *(const u16x8*)&Vl[(h8 * 16 + lq) * 64 +
                                      (((kk * 4 + g) ^ lsw) * 8)];
        ao[h8] = mfma16x16(pf[kk], vf, ao[h8]);
      }
  }

  if (!split) {
    float linv = 1.f / l_run;
    float inv[4];
#pragma unroll
    for (int r = 0; r < 4; ++r) inv[r] = __shfl(linv, g * 4 + r);
    float* Og = out + (size_t)(b * T_DIM + rowq) * H_DIM;
#pragma unroll
    for (int h8 = 0; h8 < 8; ++h8)
#pragma unroll
      for (int r = 0; r < 4; ++r)
        Og[(size_t)(g * 4 + r) * H_DIM + h8 * 16 + lq] = ao[h8][r] * inv[r];
  } else {
    u16* Op = Opart + (size_t)pid * 16384 + (size_t)(wave * 16) * H_DIM;
#pragma unroll
    for (int h8 = 0; h8 < 8; ++h8)
#pragma unroll
      for (int r = 0; r < 4; ++r)
        Op[(g * 4 + r) * H_DIM + h8 * 16 + lq] = f2bf(ao[h8][r]);
    if (lane < 16) {  // lane lq holds m/l for q-local row wave*16+lq
      float* mlp = ml + (size_t)pid * 256;
      mlp[wave * 16 + lane] = m_run;
      mlp[128 + wave * 16 + lane] = l_run;
    }
  }
}

// --------------------------------------------------------------- combine ----
// grid (128, 4): 512 blocks; each merges 32 rows of a 128-row q-block
// (<=16 bf16 partials), 16 accumulators/thread.
__global__ __launch_bounds__(256) void combine_kernel(
    const u16* __restrict__ Opart, const float* __restrict__ ml,
    float* __restrict__ out) {
  const int blk = blockIdx.x;
  const int qb = blk >> 2;
  const int sub = blk & 3;
  const int b = blockIdx.y;
  const int t = threadIdx.x;
  const int row = sub * 32 + (t >> 3);  // row within the 128-row q-block
  const int colb = (t & 7) * 16;
  const int a = qb >> 1;
  const int n = a + 1;
  const int base = a * (a + 1) + (qb & 1) * (a + 1);
  const int pid0 = b * EPB + base;

  float M = -INFINITY;
  for (int i = 0; i < n; ++i)
    M = fmaxf(M, ml[(size_t)(pid0 + i) * 256 + row]);

  float L = 0.f;
  float o[16] = {};
  for (int i = 0; i < n; ++i) {
    const size_t mb = (size_t)(pid0 + i) * 256;
    float sc = __expf(ml[mb + row] - M);
    L += sc * ml[mb + 128 + row];
    const u16* Op = Opart + (size_t)(pid0 + i) * 16384 + row * H_DIM + colb;
#pragma unroll
    for (int p = 0; p < 2; ++p) {
      u16x8 v = *(const u16x8*)&Op[p * 8];
#pragma unroll
      for (int e = 0; e < 8; ++e) o[p * 8 + e] += sc * bf2f(v[e]);
    }
  }
  float inv = 1.f / L;
  float* Og = out + ((size_t)b * T_DIM + qb * 128 + row) * H_DIM + colb;
#pragma unroll
  for (int p = 0; p < 4; ++p) {
    f32x4 v = {o[p * 4] * inv, o[p * 4 + 1] * inv, o[p * 4 + 2] * inv,
               o[p * 4 + 3] * inv};
    *(f32x4*)&Og[p * 4] = v;
  }
}

// ---------------------------------------------------------------- launch ----
extern "C" void kernel_launch(void* const* d_in, const int* in_sizes, int n_in,
                              void* d_out, int out_size, void* d_ws,
                              size_t ws_size, hipStream_t stream) {
  const float* x = (const float*)d_in[0];
  const float* wk = (const float*)d_in[1];
  const float* wq = (const float*)d_in[2];
  const float* wv = (const float*)d_in[3];
  float* out = (float*)d_out;
  char* ws = (char*)d_ws;

  u16* Wf = (u16*)ws;
  u16* Qb = (u16*)(ws + 786432);
  u16* Kb = (u16*)(ws + 786432 + 4194304);
  u16* Vt = (u16*)(ws + 786432 + 8388608);
  u16* Opart = (u16*)(ws + 13369344);
  float* ml = (float*)(ws + 49020928);

  const int split = (ws_size >= WS_SPLIT_NEED) ? 1 : 0;

  prep_w_kernel<<<192, 256, 0, stream>>>(wk, wq, wv, Wf);
  proj_kernel<<<512, 512, 0, stream>>>(x, Wf, Qb, Kb, Vt);
  if (split) {
    attn_kernel<<<4 * EPB, 512, 0, stream>>>(Qb, Kb, Vt, out, Opart, ml, 1);
    combine_kernel<<<dim3(128, 4), 256, 0, stream>>>(Opart, ml, out);
  } else {
    attn_kernel<<<128, 512, 0, stream>>>(Qb, Kb, Vt, out, Opart, ml, 0);
  }
}

// Round 19
// 83.975 us; speedup vs baseline: 1.4295x; 1.4295x over previous
//
#include <hip/hip_runtime.h>
#include <hip/hip_bf16.h>

// Single-head causal self-attention, B=4 T=4096 C=1024 H=128, f32 in/out.
// FINAL BEST CONFIG (= R17, reproduced at 84.2 us; R18's (512,6) spilled:
// compiler allocates 40 VGPR + 126MB scratch traffic -> attn 80 us. Keep
// (512,4): VGPR 60, no spill, attn ~41.8 us).
// prep_w: W -> Wf bf16 in MFMA-FRAGMENT ORDER (Q prescaled by H^-0.5).
// proj:   512 blocks x 32 rows, 512 threads (8 waves, 3 n-frags each);
//         x staged ONCE in LDS (32x1024 bf16 = 64KB, XOR-swizzled); k-loop
//         BARRIER-FREE: W frags straight from L2 (coalesced), x from LDS.
// attn:   flash causal, 512-thr: QBLK=128 = 8 waves x 16 q-rows, K/V staged
//         via global_load_lds into XOR-swizzled LDS. SWAPPED QK^T: lane holds
//         one q-row's 16 S-values -> in-lane softmax tree + 2 shfl.
//         P spill packed as ds_write_b64. kv-split chunk=256, heavy-first,
//         XCD-pinned batch. Partials bf16.
// combine: grid (128,4): 32 rows/block, <=16 partials, 16 acc/thread.
//
// ws map (bytes):
//   Wf    [0,        786432)
//   Qb    [786432,   +4MB)
//   Kb    [+4MB)
//   Vt    [+4MB)                      -> 13369344
//   Opart [13369344, +1088*32KB)      -> 49020928   (bf16)
//   ml    [49020928, +1114112)        -> 50135040

typedef unsigned short u16;
typedef __attribute__((ext_vector_type(8))) __bf16 bf16x8;
typedef __attribute__((ext_vector_type(8))) u16 u16x8;
typedef __attribute__((ext_vector_type(4))) u16 u16x4;
typedef __attribute__((ext_vector_type(4))) float f32x4;

#define T_DIM 4096
#define C_DIM 1024
#define H_DIM 128
#define EPB 272  // entries per batch: sum_{qb<32} ceil((qb+1)/2), chunk=256
#define WS_SPLIT_NEED 50135040ull

static __device__ __forceinline__ f32x4 mfma16x16(u16x8 a, u16x8 b, f32x4 c) {
  return __builtin_amdgcn_mfma_f32_16x16x32_bf16(
      __builtin_bit_cast(bf16x8, a), __builtin_bit_cast(bf16x8, b), c, 0, 0, 0);
}

static __device__ __forceinline__ u16 f2bf(float f) {
  __hip_bfloat16 h = __float2bfloat16(f);
  return __builtin_bit_cast(u16, h);
}

static __device__ __forceinline__ float bf2f(u16 u) {
  unsigned x = (unsigned)u << 16;
  return __builtin_bit_cast(float, x);
}

// async global->LDS, 16B per lane; lptr must be wave-uniform base.
static __device__ __forceinline__ void gll16(const u16* g, u16* l) {
  __builtin_amdgcn_global_load_lds(
      (const __attribute__((address_space(1))) void*)(void*)g,
      (__attribute__((address_space(3))) void*)l, 16, 0, 0);
}

// ---------------------------------------------------------------- prep_w ----
// grid 192 x 256: each thread emits one u16x8 of Wf (coalesced writes).
__global__ __launch_bounds__(256) void prep_w_kernel(
    const float* __restrict__ wk, const float* __restrict__ wq,
    const float* __restrict__ wv, u16* __restrict__ Wf) {
  const int oid = blockIdx.x * 256 + threadIdx.x;  // [0, 49152)
  const int w = oid >> 14;
  const int r = oid & 16383;
  const int nb = r >> 11;
  const int kb = (r >> 6) & 31;
  const int lane = r & 63;
  const int g = lane >> 4, lq = lane & 15;
  const float* W = (w == 0) ? wk : (w == 1) ? wq : wv;
  const float sc = (w == 1) ? 0.08838834764831845f : 1.0f;
  const int k0 = kb * 32 + g * 8;
  const int n = nb * 16 + lq;
  u16x8 o;
#pragma unroll
  for (int j = 0; j < 8; ++j) o[j] = f2bf(W[(size_t)(k0 + j) * H_DIM + n] * sc);
  *(u16x8*)&Wf[(size_t)oid * 8] = o;
}

// ------------------------------------------------------------------ proj ----
// 512 blocks x 32 rows, 512 threads: 8 waves, wave owns cols384
// wave*48 + j*16 + lq (j=0..2). Barrier-free k-loop, W frags from L2.
__global__ __launch_bounds__(512, 2) void proj_kernel(
    const float* __restrict__ x, const u16* __restrict__ Wf,
    u16* __restrict__ Qb, u16* __restrict__ Kb, u16* __restrict__ Vt) {
  __shared__ __attribute__((aligned(16))) u16 smem[32 * 1024];  // 64 KB
  const int m0 = blockIdx.x * 32;
  const int t = threadIdx.x;
  const int wave = t >> 6, lane = t & 63;
  const int g = lane >> 4, lq = lane & 15;
  const int lsw = lq & 7;

  // stage x: 32 rows x 1024 cols f32 -> bf16, swizzled 16B chunks
#pragma unroll
  for (int p = 0; p < 8; ++p) {
    int c = p * 512 + t;          // chunk id [0, 4096)
    int row = c >> 7, cc = c & 127;
    const float* xp = &x[(size_t)(m0 + row) * C_DIM + cc * 8];
    float4 v0 = *(const float4*)xp;
    float4 v1 = *(const float4*)(xp + 4);
    u16x8 bv;
    bv[0] = f2bf(v0.x); bv[1] = f2bf(v0.y); bv[2] = f2bf(v0.z); bv[3] = f2bf(v0.w);
    bv[4] = f2bf(v1.x); bv[5] = f2bf(v1.y); bv[6] = f2bf(v1.z); bv[7] = f2bf(v1.w);
    *(u16x8*)&smem[row * 1024 + ((cc ^ (row & 7)) * 8)] = bv;
  }
  __syncthreads();

  f32x4 acc[2][3] = {};

  for (int k0 = 0; k0 < C_DIM; k0 += 64) {  // NO barriers inside
    const int kb0 = k0 >> 5;
#pragma unroll
    for (int kk = 0; kk < 2; ++kk) {
      u16x8 af[2], bfr[3];
#pragma unroll
      for (int i = 0; i < 2; ++i)
        af[i] = *(const u16x8*)&smem[(i * 16 + lq) * 1024 +
                                     ((((k0 >> 3) + kk * 4 + g) ^ lsw) * 8)];
#pragma unroll
      for (int j = 0; j < 3; ++j) {
        int nb = wave * 3 + j;  // frag covers cols nb*16..+15
        bfr[j] = *(const u16x8*)&Wf[(size_t)(nb * 32 + kb0 + kk) * 512 +
                                    lane * 8];
      }
#pragma unroll
      for (int i = 0; i < 2; ++i)
#pragma unroll
        for (int j = 0; j < 3; ++j)
          acc[i][j] = mfma16x16(af[i], bfr[j], acc[i][j]);
    }
  }

#pragma unroll
  for (int j = 0; j < 3; ++j) {  // K and Q direct writes (wave-uniform branch)
    const int c384 = wave * 48 + j * 16;
    const int which = c384 >> 7;
    const int col = (c384 & 127) + lq;
    if (which == 0) {
#pragma unroll
      for (int i = 0; i < 2; ++i)
#pragma unroll
        for (int r = 0; r < 4; ++r)
          Kb[(size_t)(m0 + i * 16 + g * 4 + r) * H_DIM + col] =
              f2bf(acc[i][j][r]);
    } else if (which == 1) {
#pragma unroll
      for (int i = 0; i < 2; ++i)
#pragma unroll
        for (int r = 0; r < 4; ++r)
          Qb[(size_t)(m0 + i * 16 + g * 4 + r) * H_DIM + col] =
              f2bf(acc[i][j][r]);  // Wq prescaled in prep_w
    }
  }
  __syncthreads();  // all x-LDS reads done; reuse smem for V transpose
#pragma unroll
  for (int j = 0; j < 3; ++j) {  // V -> LDS transposed [128 h][32 m] pad 40
    const int c384 = wave * 48 + j * 16;
    if ((c384 >> 7) == 2) {
      const int v = (c384 & 127) + lq;
#pragma unroll
      for (int i = 0; i < 2; ++i)
#pragma unroll
        for (int r = 0; r < 4; ++r)
          smem[v * 40 + i * 16 + g * 4 + r] = f2bf(acc[i][j][r]);
    }
  }
  __syncthreads();
  {
    const int b = m0 >> 12;
    const int t0 = m0 & 4095;
    int h = t >> 2, mc = (t & 3) * 8;  // 512 thr x 8 = 128x32
    *(u16x8*)&Vt[(size_t)b * (H_DIM * T_DIM) + (size_t)h * T_DIM + t0 + mc] =
        *(const u16x8*)&smem[h * 40 + mc];
  }
}

// ------------------------------------------------------------------ attn ----
// 512 threads: 8 waves x 16 q-rows = QBLK 128 sharing one K/V staging via
// global_load_lds (pre-swizzled source). SWAPPED QK^T: s = mfma(K,Q) puts a
// full q-row (16 S values) in each lane -> in-lane softmax tree + 2 shfl.
// P spill: 4x ds_write_b64 per wave (packed). launch_bounds(512,4): 2
// blocks/CU, VGPR 60, no spill ((512,6) forces 40 VGPR + scratch — R7/R18).
// split: 1088 blocks, XCD-pinned batch, heavy entries first, chunk=256.
__global__ __launch_bounds__(512, 4) void attn_kernel(
    const u16* __restrict__ Qb, const u16* __restrict__ Kb,
    const u16* __restrict__ Vt, float* __restrict__ out,
    u16* __restrict__ Opart, float* __restrict__ ml, int split) {
  __shared__ __attribute__((aligned(16))) u16 Kl[64 * 128];  // swizzled
  __shared__ __attribute__((aligned(16))) u16 Vl[128 * 64];  // swizzled
  __shared__ __attribute__((aligned(16))) u16 Pl[8][16 * 72];
  const int t = threadIdx.x;
  const int wave = t >> 6, lane = t & 63;
  const int g = lane >> 4, lq = lane & 15;
  const int lsw = lane & 7;  // read-side swizzle key (= row&7 for row=16nf+lq)

  int b, qb, kvb, kve, pid;
  if (split) {
    int bid = (int)blockIdx.x;  // 1088 linear
    int xcd = bid & 7;
    b = xcd >> 1;  // batch pinned to an XCD pair -> K/V L2-local
    int e = (EPB - 1) - ((bid >> 3) * 2 + (bid & 1));  // heavy-first
    int a = 0;
#pragma unroll
    for (int c = 1; c <= 15; ++c)
      if (e >= c * (c + 1)) a = c;
    int off = e - a * (a + 1);
    int d = off / (a + 1);
    int ch = off - d * (a + 1);
    qb = 2 * a + d;
    kvb = ch * 256;
    pid = b * EPB + e;
    int kv_full = qb * 128 + 128;
    kve = (kvb + 256 < kv_full) ? kvb + 256 : kv_full;
  } else {
    b = (int)blockIdx.x & 3;
    qb = 31 - ((int)blockIdx.x >> 2);
    kvb = 0;
    kve = qb * 128 + 128;
    pid = 0;
  }
  const int rowq = qb * 128 + wave * 16;  // wave's first q-row
  const int qrow = rowq + lq;             // this lane's q row (swapped layout)

  u16x8 qf[4];  // 16 q-rows x 128, A-frag layout (prescaled)
  {
    const u16* Qp = Qb + (size_t)(b * T_DIM + qrow) * H_DIM;
#pragma unroll
    for (int c = 0; c < 4; ++c) qf[c] = *(const u16x8*)&Qp[c * 32 + g * 8];
  }

  f32x4 ao[8] = {};
  float m_run = -INFINITY, l_run = 0.f;  // per-lane scalars (q = qrow)

  const u16* Kg0 = Kb + (size_t)b * T_DIM * H_DIM;
  const u16* Vg0 = Vt + (size_t)b * H_DIM * T_DIM;

  for (int kv0 = kvb; kv0 < kve; kv0 += 64) {
    __syncthreads();
    // K tile [64][128]: 2 issues/wave, each 4 rows (1KB).
#pragma unroll
    for (int i = 0; i < 2; ++i) {
      int r0 = (i * 8 + wave) * 4;
      int r = r0 + (lane >> 4);
      int csrc = (lane & 15) ^ (r & 7);
      gll16(&Kg0[(size_t)(kv0 + r) * H_DIM + csrc * 8], &Kl[r0 * 128]);
    }
    // V tile [128][64]: 2 issues/wave, each 8 rows (1KB).
#pragma unroll
    for (int i = 0; i < 2; ++i) {
      int h0 = (i * 8 + wave) * 8;
      int h = h0 + (lane >> 3);
      int csrc = (lane & 7) ^ (lane >> 3);
      gll16(&Vg0[(size_t)h * T_DIM + kv0 + csrc * 8], &Vl[h0 * 64]);
    }
    __syncthreads();

    if (kv0 > rowq + 15) continue;  // fully masked for this wave (uniform)

    // S^T = mfma(K, Q): lane (g,lq) holds S[qrow][kv0 + nf*16 + 4g + r]
    f32x4 s[4];
#pragma unroll
    for (int nf = 0; nf < 4; ++nf) s[nf] = f32x4{0.f, 0.f, 0.f, 0.f};
#pragma unroll
    for (int nf = 0; nf < 4; ++nf)
#pragma unroll
      for (int c = 0; c < 4; ++c) {
        u16x8 kf = *(const u16x8*)&Kl[(nf * 16 + lq) * 128 +
                                      (((c * 4 + g) ^ lsw) * 8)];
        s[nf] = mfma16x16(kf, qf[c], s[nf]);
      }

    if (kv0 + 63 > rowq) {  // diagonal overlap: elementwise causal mask
      const int kb = kv0 + g * 4;
#pragma unroll
      for (int nf = 0; nf < 4; ++nf)
#pragma unroll
        for (int r = 0; r < 4; ++r)
          if (kb + nf * 16 + r > qrow) s[nf][r] = -INFINITY;
    }

    // softmax: in-lane tree over 16 values + cross-g (xor 16, 32)
    float t0 = fmaxf(fmaxf(s[0][0], s[0][1]), fmaxf(s[0][2], s[0][3]));
    float t1 = fmaxf(fmaxf(s[1][0], s[1][1]), fmaxf(s[1][2], s[1][3]));
    float t2 = fmaxf(fmaxf(s[2][0], s[2][1]), fmaxf(s[2][2], s[2][3]));
    float t3 = fmaxf(fmaxf(s[3][0], s[3][1]), fmaxf(s[3][2], s[3][3]));
    float pmax = fmaxf(fmaxf(t0, t1), fmaxf(t2, t3));
    pmax = fmaxf(pmax, __shfl_xor(pmax, 16));
    pmax = fmaxf(pmax, __shfl_xor(pmax, 32));

    float mn = fmaxf(m_run, pmax);
    float al = __expf(m_run - mn);
    m_run = mn;
#pragma unroll
    for (int nf = 0; nf < 4; ++nf)
#pragma unroll
      for (int r = 0; r < 4; ++r) s[nf][r] = __expf(s[nf][r] - mn);
    float u0 = (s[0][0] + s[0][1]) + (s[0][2] + s[0][3]);
    float u1 = (s[1][0] + s[1][1]) + (s[1][2] + s[1][3]);
    float u2 = (s[2][0] + s[2][1]) + (s[2][2] + s[2][3]);
    float u3 = (s[3][0] + s[3][1]) + (s[3][2] + s[3][3]);
    float ps = (u0 + u1) + (u2 + u3);
    ps += __shfl_xor(ps, 16);
    ps += __shfl_xor(ps, 32);
    l_run = l_run * al + ps;

    // defer-rescale: only broadcast+rescale when some row's max moved
    if (!__all(al == 1.f)) {
      float alr[4];
#pragma unroll
      for (int r = 0; r < 4; ++r) alr[r] = __shfl(al, g * 4 + r);
#pragma unroll
      for (int h8 = 0; h8 < 8; ++h8)
#pragma unroll
        for (int r = 0; r < 4; ++r) ao[h8][r] *= alr[r];
    }

    // P (swapped layout) -> per-wave LDS, PACKED b64 writes (4 instrs)
#pragma unroll
    for (int nf = 0; nf < 4; ++nf) {
      u16x4 pw;
#pragma unroll
      for (int r = 0; r < 4; ++r) pw[r] = f2bf(s[nf][r]);
      *(u16x4*)&Pl[wave][lq * 72 + nf * 16 + g * 4] = pw;
    }

    u16x8 pf[2];
#pragma unroll
    for (int kk = 0; kk < 2; ++kk)
      pf[kk] = *(const u16x8*)&Pl[wave][lq * 72 + kk * 32 + g * 8];
#pragma unroll
    for (int h8 = 0; h8 < 8; ++h8)
#pragma unroll
      for (int kk = 0; kk < 2; ++kk) {
        u16x8 vf = *(const u16x8*)&Vl[(h8 * 16 + lq) * 64 +
                                      (((kk * 4 + g) ^ lsw) * 8)];
        ao[h8] = mfma16x16(pf[kk], vf, ao[h8]);
      }
  }

  if (!split) {
    float linv = 1.f / l_run;
    float inv[4];
#pragma unroll
    for (int r = 0; r < 4; ++r) inv[r] = __shfl(linv, g * 4 + r);
    float* Og = out + (size_t)(b * T_DIM + rowq) * H_DIM;
#pragma unroll
    for (int h8 = 0; h8 < 8; ++h8)
#pragma unroll
      for (int r = 0; r < 4; ++r)
        Og[(size_t)(g * 4 + r) * H_DIM + h8 * 16 + lq] = ao[h8][r] * inv[r];
  } else {
    u16* Op = Opart + (size_t)pid * 16384 + (size_t)(wave * 16) * H_DIM;
#pragma unroll
    for (int h8 = 0; h8 < 8; ++h8)
#pragma unroll
      for (int r = 0; r < 4; ++r)
        Op[(g * 4 + r) * H_DIM + h8 * 16 + lq] = f2bf(ao[h8][r]);
    if (lane < 16) {  // lane lq holds m/l for q-local row wave*16+lq
      float* mlp = ml + (size_t)pid * 256;
      mlp[wave * 16 + lane] = m_run;
      mlp[128 + wave * 16 + lane] = l_run;
    }
  }
}

// --------------------------------------------------------------- combine ----
// grid (128, 4): 512 blocks; each merges 32 rows of a 128-row q-block
// (<=16 bf16 partials), 16 accumulators/thread.
__global__ __launch_bounds__(256) void combine_kernel(
    const u16* __restrict__ Opart, const float* __restrict__ ml,
    float* __restrict__ out) {
  const int blk = blockIdx.x;
  const int qb = blk >> 2;
  const int sub = blk & 3;
  const int b = blockIdx.y;
  const int t = threadIdx.x;
  const int row = sub * 32 + (t >> 3);  // row within the 128-row q-block
  const int colb = (t & 7) * 16;
  const int a = qb >> 1;
  const int n = a + 1;
  const int base = a * (a + 1) + (qb & 1) * (a + 1);
  const int pid0 = b * EPB + base;

  float M = -INFINITY;
  for (int i = 0; i < n; ++i)
    M = fmaxf(M, ml[(size_t)(pid0 + i) * 256 + row]);

  float L = 0.f;
  float o[16] = {};
  for (int i = 0; i < n; ++i) {
    const size_t mb = (size_t)(pid0 + i) * 256;
    float sc = __expf(ml[mb + row] - M);
    L += sc * ml[mb + 128 + row];
    const u16* Op = Opart + (size_t)(pid0 + i) * 16384 + row * H_DIM + colb;
#pragma unroll
    for (int p = 0; p < 2; ++p) {
      u16x8 v = *(const u16x8*)&Op[p * 8];
#pragma unroll
      for (int e = 0; e < 8; ++e) o[p * 8 + e] += sc * bf2f(v[e]);
    }
  }
  float inv = 1.f / L;
  float* Og = out + ((size_t)b * T_DIM + qb * 128 + row) * H_DIM + colb;
#pragma unroll
  for (int p = 0; p < 4; ++p) {
    f32x4 v = {o[p * 4] * inv, o[p * 4 + 1] * inv, o[p * 4 + 2] * inv,
               o[p * 4 + 3] * inv};
    *(f32x4*)&Og[p * 4] = v;
  }
}

// ---------------------------------------------------------------- launch ----
extern "C" void kernel_launch(void* const* d_in, const int* in_sizes, int n_in,
                              void* d_out, int out_size, void* d_ws,
                              size_t ws_size, hipStream_t stream) {
  const float* x = (const float*)d_in[0];
  const float* wk = (const float*)d_in[1];
  const float* wq = (const float*)d_in[2];
  const float* wv = (const float*)d_in[3];
  float* out = (float*)d_out;
  char* ws = (char*)d_ws;

  u16* Wf = (u16*)ws;
  u16* Qb = (u16*)(ws + 786432);
  u16* Kb = (u16*)(ws + 786432 + 4194304);
  u16* Vt = (u16*)(ws + 786432 + 8388608);
  u16* Opart = (u16*)(ws + 13369344);
  float* ml = (float*)(ws + 49020928);

  const int split = (ws_size >= WS_SPLIT_NEED) ? 1 : 0;

  prep_w_kernel<<<192, 256, 0, stream>>>(wk, wq, wv, Wf);
  proj_kernel<<<512, 512, 0, stream>>>(x, Wf, Qb, Kb, Vt);
  if (split) {
    attn_kernel<<<4 * EPB, 512, 0, stream>>>(Qb, Kb, Vt, out, Opart, ml, 1);
    combine_kernel<<<dim3(128, 4), 256, 0, stream>>>(Opart, ml, out);
  } else {
    attn_kernel<<<128, 512, 0, stream>>>(Qb, Kb, Vt, out, Opart, ml, 0);
  }
}